// Round 22
// baseline (49.124 us; speedup 1.0000x reference)
//
#include <hip/hip_runtime.h>
#include <hip/hip_bf16.h>

// Problem constants (S4Layer: T=4096, B=16, D=128, S=256)
#define T_  4096
#define B_  16
#define D_  128
#define S_  256
#define WND 64             // GEMM t-tile (chunk pair = 2 scan chunks)
#define C4  (T_/WND)       // 64 GEMM chunks
#define SC  32             // scan chunk length
#define NSC (T_/SC)        // 128 scan chunks
#define PSTR 520           // P row stride (pad-8: conflict-free u16 writes)

using bf8   = __attribute__((ext_vector_type(8))) short;   // 8 bf16 (4 VGPRs)
using f32x4 = __attribute__((ext_vector_type(4))) float;   // MFMA acc

__device__ inline float bfbits(unsigned short h) {
    return __builtin_bit_cast(float, (unsigned)h << 16);
}
__device__ inline unsigned short bf16bits(float f) {
    return __hip_bfloat16_raw(__float2bfloat16(f)).x;
}

// ---------------- K1: parameters (hoisted, computed ONCE) -------------------
__global__ __launch_bounds__(256) void k_params(
        const float* __restrict__ lna, const float* __restrict__ bmat,
        const float* __restrict__ ldt,
        float* __restrict__ abar, float* __restrict__ a32,
        __hip_bfloat16* __restrict__ bbar) {
    if (blockIdx.x < 128) {
        int idx = blockIdx.x * 256 + threadIdx.x;   // (s,d)
        int s = idx >> 7;
        float la = fminf(fmaxf(lna[s], -8.f), 4.f);
        float ar = -expf(la);
        float lt = fminf(fmaxf(ldt[s], -8.f), 1.f);
        float dt = expf(lt);
        float xx = dt * ar;
        float ratio = (fabsf(xx) < 1e-6f) ? dt : (expm1f(xx) / ar);
        bbar[idx] = __float2bfloat16(ratio * bmat[idx]);
    } else {
        int s = threadIdx.x;
        float la = fminf(fmaxf(lna[s], -8.f), 4.f);
        float ar = -expf(la);
        float lt = fminf(fmaxf(ldt[s], -8.f), 1.f);
        float dt = expf(lt);
        float ab = expf(dt * ar);
        abar[s] = ab;
        float p = ab;
#pragma unroll
        for (int j = 0; j < 5; ++j) p *= p;     // a^32 by squaring
        a32[s] = p;
    }
}

// ---------------- K2: 8-wave 2-barrier double-buffered GEMM + e32 ----------
// Block (bx,b), 512 threads = 8 waves, chunks c0=2bx, c0+1 (R21 structure).
// Wave w owns s-stripe [w*32,(w+1)*32). Epilogue emits TWO half-chunk
// partials e32[2c+h] (Horner weight a^(31-t'') over each 32-row half) so the
// scan can run at 32-t granularity. Only the two A-stage barriers remain.
__global__ __launch_bounds__(512, 4) void k_gemm(
        const float* __restrict__ x, const __hip_bfloat16* __restrict__ bbar,
        const float* __restrict__ abar,
        __hip_bfloat16* __restrict__ ub, float* __restrict__ e32) {
    const int c0 = blockIdx.x * 2, b = blockIdx.y;
    __shared__ char LDS[32768 + WND * PSTR];   // A0 @0, A1 @16K, P @32K
    char* A0 = LDS;
    char* A1 = LDS + 16384;
    char* P  = LDS + 32768;
    const int tid = threadIdx.x, lane = tid & 63, w = tid >> 6;   // w in 0..7
    const int l15 = lane & 15, l4 = lane >> 4;
    const int srow = tid >> 5, sseg = tid & 31;    // stage: 16 rows x 32 segs

    // B fragments: wave w owns s in [w*32,(w+1)*32), j = 0,1
    bf8 bfrag[2][4];
#pragma unroll
    for (int j = 0; j < 2; ++j) {
        int s = w * 32 + j * 16 + l15;
#pragma unroll
        for (int kk = 0; kk < 4; ++kk)
            bfrag[j][kk] = *(const bf8*)((const short*)bbar + s * D_ + kk * 32 + l4 * 8);
    }

#define LOADX(dst, cc)                                                         \
    _Pragma("unroll")                                                          \
    for (int k = 0; k < 4; ++k)                                                \
        dst[k] = *(const float4*)(x + ((size_t)((cc) * WND + srow + k * 16) * B_ + b) * D_ + sseg * 4);

#define CVTWRITE(A, src)                                                       \
    _Pragma("unroll")                                                          \
    for (int k = 0; k < 4; ++k) {                                              \
        int row = srow + k * 16;                                               \
        __hip_bfloat162 lo = __float22bfloat162_rn(make_float2(src[k].x, src[k].y)); \
        __hip_bfloat162 hi = __float22bfloat162_rn(make_float2(src[k].z, src[k].w)); \
        uint2 pk = { *(unsigned*)&lo, *(unsigned*)&hi };                       \
        *(uint2*)((A) + ((row * 256 + sseg * 8) ^ ((row & 7) << 4))) = pk;     \
    }

#define MFMA_TILE(A)                                                           \
    _Pragma("unroll")                                                          \
    for (int i = 0; i < 4; ++i) {                                              \
        bf8 af[4];                                                             \
        int tr = i * 16 + l15;                                                 \
        _Pragma("unroll")                                                      \
        for (int kk = 0; kk < 4; ++kk) {                                       \
            int off = (tr * 256 + kk * 64 + l4 * 16) ^ ((tr & 7) << 4);        \
            af[kk] = *(const bf8*)((A) + off);                                 \
        }                                                                      \
        _Pragma("unroll")                                                      \
        for (int j = 0; j < 2; ++j)                                            \
            _Pragma("unroll")                                                  \
            for (int kk = 0; kk < 4; ++kk)                                     \
                acc[i][j] = __builtin_amdgcn_mfma_f32_16x16x32_bf16(           \
                                af[kk], bfrag[j][kk], acc[i][j], 0, 0, 0);     \
    }

    // Epilogue: P writes (pad-520 rows, conflict-free) + TWO half-chunk
    // Horner partials: e_lo over rows 0..31 (i=0,1), e_hi rows 32..63 (i=2,3),
    // each = (inner_a * a16 + inner_b) * lf = sum a^(31-t'') * P[t''].
#define EPILOGUE(cc)                                                           \
    _Pragma("unroll")                                                          \
    for (int j = 0; j < 2; ++j) {                                              \
        int s = w * 32 + j * 16 + l15;                                         \
        float a  = abar[s];                                                    \
        float a2 = a * a, a4 = a2 * a2, a8 = a4 * a4, a16 = a8 * a8;           \
        float lf = (l4 == 0) ? a8 * a4 : (l4 == 1) ? a8 : (l4 == 2) ? a4 : 1.f;\
        float elo = 0.f, ehi = 0.f;                                            \
        _Pragma("unroll")                                                      \
        for (int i = 0; i < 4; ++i) {                                          \
            unsigned short h0 = bf16bits(acc[i][j][0]);                        \
            unsigned short h1 = bf16bits(acc[i][j][1]);                        \
            unsigned short h2 = bf16bits(acc[i][j][2]);                        \
            unsigned short h3 = bf16bits(acc[i][j][3]);                        \
            float inner = bfbits(h0);                                          \
            inner = fmaf(inner, a, bfbits(h1));                                \
            inner = fmaf(inner, a, bfbits(h2));                                \
            inner = fmaf(inner, a, bfbits(h3));                                \
            if (i < 2) elo = (i == 0) ? inner : fmaf(elo, a16, inner);         \
            else       ehi = (i == 2) ? inner : fmaf(ehi, a16, inner);         \
            int row0 = i * 16 + l4 * 4;                                        \
            *(unsigned short*)(P + (row0    ) * PSTR + s * 2) = h0;            \
            *(unsigned short*)(P + (row0 + 1) * PSTR + s * 2) = h1;            \
            *(unsigned short*)(P + (row0 + 2) * PSTR + s * 2) = h2;            \
            *(unsigned short*)(P + (row0 + 3) * PSTR + s * 2) = h3;            \
        }                                                                      \
        elo *= lf; ehi *= lf;                                                  \
        elo += __shfl_xor(elo, 16);                                            \
        elo += __shfl_xor(elo, 32);                                            \
        ehi += __shfl_xor(ehi, 16);                                            \
        ehi += __shfl_xor(ehi, 32);                                            \
        if (l4 == 0) {                                                         \
            e32[((size_t)((cc) * 2    ) * B_ + b) * S_ + s] = elo;             \
            e32[((size_t)((cc) * 2 + 1) * B_ + b) * S_ + s] = ehi;             \
        }                                                                      \
    }

    // Wave-stripe copy: wave w copies bytes [w*64,(w+1)*64) of each row
    // (exactly what it wrote -> same-wave dep, NO barrier).
#define STRIPECOPY(cc)                                                         \
    {                                                                          \
        char* gp = (char*)(ub + ((size_t)b * T_ + (cc) * WND) * S_) + w * 64;  \
        const int lrow = lane >> 2, lo = (lane & 3) * 16;                      \
        _Pragma("unroll")                                                      \
        for (int k = 0; k < 4; ++k) {                                          \
            int row = k * 16 + lrow;                                           \
            uint4 v = *(uint4*)(P + row * PSTR + w * 64 + lo);                 \
            *(uint4*)(gp + (size_t)row * 512 + lo) = v;                        \
        }                                                                      \
    }

    float4 xr[4];
    LOADX(xr, c0)
    CVTWRITE(A0, xr)
    __syncthreads();                   // A0 ready (cross-wave)

    float4 xr1[4];
    LOADX(xr1, c0 + 1)                 // issue early; hides under chunk-0

    {   // ---- chunk 0: MFMA -> epilogue -> stripe-copy (barrier-free) ----
        f32x4 acc[4][2] = {};
        MFMA_TILE(A0)
        EPILOGUE(c0)
        STRIPECOPY(c0)
    }
    CVTWRITE(A1, xr1)
    __syncthreads();                   // A1 ready (cross-wave)

    {   // ---- chunk 1: MFMA -> epilogue -> stripe-copy (barrier-free) ----
        f32x4 acc[4][2] = {};
        MFMA_TILE(A1)
        EPILOGUE(c0 + 1)
        STRIPECOPY(c0 + 1)
    }
}

// ---------------- K3: carry + 32-t scan + out, x2 s-vectorized -------------
// Grid (128, 8): 1024 blocks x 4 waves = 16 waves/CU (2x R21's scan TLP).
// Block (cc,g): wave w -> b = g*2 + (w>>1), s-half = (w&1); lane -> 2 s.
// Carry over e32 with aw=a^32: truncated 32-window if aw^32 < 1e-10 for all
// lanes (residual < 1e-10; true here), else exact 128-trip predicated loop.
__global__ __launch_bounds__(256) void k_scan(
        const __hip_bfloat16* __restrict__ ub, const float* __restrict__ e32,
        const float* __restrict__ abar, const float* __restrict__ a32,
        const float* __restrict__ z0, float* __restrict__ out) {
    const int cc = blockIdx.x, g = blockIdx.y;
    const int w = threadIdx.x >> 6, lane = threadIdx.x & 63;
    const int b = g * 2 + (w >> 1);
    const int s0 = (w & 1) * 128 + lane * 2;

    float2 a  = *(const float2*)(abar + s0);
    float2 aw = *(const float2*)(a32 + s0);
    float2 z  = *(const float2*)(z0 + b * S_ + s0);

    // guard: aw^32 (5 squarings)
    float gx = aw.x, gy = aw.y;
#pragma unroll
    for (int q = 0; q < 5; ++q) { gx *= gx; gy *= gy; }
    if (__all(fmaxf(gx, gy) < 1e-10f)) {
        // truncated: only the last 32 half-chunks matter
#pragma unroll
        for (int half = 0; half < 2; ++half) {
            float2 ev[16];
#pragma unroll
            for (int k = 0; k < 16; ++k) {
                int cp = cc - 32 + half * 16 + k, cpc = cp < 0 ? 0 : cp;
                ev[k] = *(const float2*)(e32 + ((size_t)cpc * B_ + b) * S_ + s0);
            }
#pragma unroll
            for (int k = 0; k < 16; ++k) {
                float zx = fmaf(aw.x, z.x, ev[k].x);
                float zy = fmaf(aw.y, z.y, ev[k].y);
                bool p = (cc - 32 + half * 16 + k) >= 0;
                z.x = p ? zx : z.x;
                z.y = p ? zy : z.y;
            }
        }
    } else {
        // exact: 128 fixed trips, batch-16 loads then predicated fma
#pragma unroll
        for (int cp0 = 0; cp0 < NSC; cp0 += 16) {
            float2 ev[16];
#pragma unroll
            for (int k = 0; k < 16; ++k)
                ev[k] = *(const float2*)(e32 + ((size_t)(cp0 + k) * B_ + b) * S_ + s0);
#pragma unroll
            for (int k = 0; k < 16; ++k) {
                float zx = fmaf(aw.x, z.x, ev[k].x);
                float zy = fmaf(aw.y, z.y, ev[k].y);
                bool p = (cp0 + k) < cc;
                z.x = p ? zx : z.x;
                z.y = p ? zy : z.y;
            }
        }
    }

    // scan own 32-t chunk, coalesced; nontemporal out stores
    const char* up = (const char*)(ub + ((size_t)b * T_ + cc * SC) * S_ + s0);
    float* op = out + ((size_t)(cc * SC) * B_ + b) * S_ + s0;
#pragma unroll 8
    for (int t = 0; t < SC; ++t) {
        ushort2 v = *(const ushort2*)up;           // 4 B/lane, 256 B/wave
        z.x = fmaf(a.x, z.x, bfbits(v.x));
        z.y = fmaf(a.y, z.y, bfbits(v.y));
        __builtin_nontemporal_store(z.x, op);
        __builtin_nontemporal_store(z.y, op + 1);
        up += S_ * 2;
        op += (size_t)B_ * S_;
    }
}

extern "C" void kernel_launch(void* const* d_in, const int* in_sizes, int n_in,
                              void* d_out, int out_size, void* d_ws, size_t ws_size,
                              hipStream_t stream) {
    const float* x   = (const float*)d_in[0];  // [T,B,D]
    const float* z0  = (const float*)d_in[1];  // [B,S]
    const float* lna = (const float*)d_in[2];  // [S]
    const float* bm  = (const float*)d_in[3];  // [S,D]
    const float* ldt = (const float*)d_in[4];  // [S]
    float* out = (float*)d_out;

    char* ws = (char*)d_ws;
    float*          abar = (float*)ws;                        // 1 KiB
    float*          a32  = (float*)(ws + 4096);               // 1 KiB
    __hip_bfloat16* bbar = (__hip_bfloat16*)(ws + 8192);      // 64 KiB
    float*          e32  = (float*)(ws + (128 << 10));        // 2 MiB [sc][b][s]
    __hip_bfloat16* ub   = (__hip_bfloat16*)(ws + (4 << 20)); // 32 MiB [b][t][s]

    k_params<<<129, 256, 0, stream>>>(lna, bm, ldt, abar, a32, bbar);
    k_gemm<<<dim3(C4 / 2, B_), 512, 0, stream>>>(x, bbar, abar, ub, e32);
    k_scan<<<dim3(NSC, B_ / 2), 256, 0, stream>>>(ub, e32, abar, a32, z0, out);
}

// Round 23
// 44.919 us; speedup vs baseline: 1.0936x; 1.0936x over previous
//
#include <hip/hip_runtime.h>
#include <hip/hip_bf16.h>

// Problem constants (S4Layer: T=4096, B=16, D=128, S=256)
#define T_  4096
#define B_  16
#define D_  128
#define S_  256
#define WND 64             // chunk length = GEMM t-tile
#define C4  (T_/WND)       // 64 chunks
#define PSTR 520           // P row stride (pad-8: conflict-free u16 writes)

using bf8   = __attribute__((ext_vector_type(8))) short;   // 8 bf16 (4 VGPRs)
using f32x4 = __attribute__((ext_vector_type(4))) float;   // MFMA acc

__device__ inline float bfbits(unsigned short h) {
    return __builtin_bit_cast(float, (unsigned)h << 16);
}
__device__ inline unsigned short bf16bits(float f) {
    return __hip_bfloat16_raw(__float2bfloat16(f)).x;
}

// ---------------- K1: parameters (hoisted, computed ONCE) -------------------
__global__ __launch_bounds__(256) void k_params(
        const float* __restrict__ lna, const float* __restrict__ bmat,
        const float* __restrict__ ldt,
        float* __restrict__ abar, float* __restrict__ a64,
        __hip_bfloat16* __restrict__ bbar) {
    if (blockIdx.x < 128) {
        int idx = blockIdx.x * 256 + threadIdx.x;   // (s,d)
        int s = idx >> 7;
        float la = fminf(fmaxf(lna[s], -8.f), 4.f);
        float ar = -expf(la);
        float lt = fminf(fmaxf(ldt[s], -8.f), 1.f);
        float dt = expf(lt);
        float xx = dt * ar;
        float ratio = (fabsf(xx) < 1e-6f) ? dt : (expm1f(xx) / ar);
        bbar[idx] = __float2bfloat16(ratio * bmat[idx]);
    } else {
        int s = threadIdx.x;
        float la = fminf(fmaxf(lna[s], -8.f), 4.f);
        float ar = -expf(la);
        float lt = fminf(fmaxf(ldt[s], -8.f), 1.f);
        float dt = expf(lt);
        float ab = expf(dt * ar);
        abar[s] = ab;
        float p = ab;
#pragma unroll
        for (int j = 0; j < 6; ++j) p *= p;     // a^64 by squaring
        a64[s] = p;
    }
}

// ---------------- K2: 8-wave SINGLE-barrier GEMM + e64 ---------------------
// Block (bx,b), 512 threads = 8 waves, chunks c0=2bx, c0+1. BOTH chunks'
// loads issue at the top; both A buffers cvt-written; ONE barrier; then the
// two chunk computes run back-to-back in wave program order (P stripes are
// wave-private -> no P barriers). setprio(1) around MFMA clusters (waves are
// at diverse phases post-barrier -> scheduler can favor matrix-pipe waves).
__global__ __launch_bounds__(512, 4) void k_gemm(
        const float* __restrict__ x, const __hip_bfloat16* __restrict__ bbar,
        const float* __restrict__ abar,
        __hip_bfloat16* __restrict__ ub, float* __restrict__ e64) {
    const int c0 = blockIdx.x * 2, b = blockIdx.y;
    __shared__ char LDS[32768 + WND * PSTR];   // A0 @0, A1 @16K, P @32K
    char* A0 = LDS;
    char* A1 = LDS + 16384;
    char* P  = LDS + 32768;
    const int tid = threadIdx.x, lane = tid & 63, w = tid >> 6;   // w in 0..7
    const int l15 = lane & 15, l4 = lane >> 4;
    const int srow = tid >> 5, sseg = tid & 31;    // stage: 16 rows x 32 segs

    // B fragments: wave w owns s in [w*32,(w+1)*32), j = 0,1
    bf8 bfrag[2][4];
#pragma unroll
    for (int j = 0; j < 2; ++j) {
        int s = w * 32 + j * 16 + l15;
#pragma unroll
        for (int kk = 0; kk < 4; ++kk)
            bfrag[j][kk] = *(const bf8*)((const short*)bbar + s * D_ + kk * 32 + l4 * 8);
    }

#define LOADX(dst, cc)                                                         \
    _Pragma("unroll")                                                          \
    for (int k = 0; k < 4; ++k)                                                \
        dst[k] = *(const float4*)(x + ((size_t)((cc) * WND + srow + k * 16) * B_ + b) * D_ + sseg * 4);

#define CVTWRITE(A, src)                                                       \
    _Pragma("unroll")                                                          \
    for (int k = 0; k < 4; ++k) {                                              \
        int row = srow + k * 16;                                               \
        __hip_bfloat162 lo = __float22bfloat162_rn(make_float2(src[k].x, src[k].y)); \
        __hip_bfloat162 hi = __float22bfloat162_rn(make_float2(src[k].z, src[k].w)); \
        uint2 pk = { *(unsigned*)&lo, *(unsigned*)&hi };                       \
        *(uint2*)((A) + ((row * 256 + sseg * 8) ^ ((row & 7) << 4))) = pk;     \
    }

#define MFMA_TILE(A)                                                           \
    _Pragma("unroll")                                                          \
    for (int i = 0; i < 4; ++i) {                                              \
        bf8 af[4];                                                             \
        int tr = i * 16 + l15;                                                 \
        _Pragma("unroll")                                                      \
        for (int kk = 0; kk < 4; ++kk) {                                       \
            int off = (tr * 256 + kk * 64 + l4 * 16) ^ ((tr & 7) << 4);        \
            af[kk] = *(const bf8*)((A) + off);                                 \
        }                                                                      \
        _Pragma("unroll")                                                      \
        for (int j = 0; j < 2; ++j)                                            \
            _Pragma("unroll")                                                  \
            for (int kk = 0; kk < 4; ++kk)                                     \
                acc[i][j] = __builtin_amdgcn_mfma_f32_16x16x32_bf16(           \
                                af[kk], bfrag[j][kk], acc[i][j], 0, 0, 0);     \
    }

    // Epilogue: P[row][s] at row stride 520B (conflict-free u16 writes) +
    // e64 Horner from bf16-rounded acc. Wave-private stripe -> no barrier.
#define EPILOGUE(cc)                                                           \
    _Pragma("unroll")                                                          \
    for (int j = 0; j < 2; ++j) {                                              \
        int s = w * 32 + j * 16 + l15;                                         \
        float a  = abar[s];                                                    \
        float a2 = a * a, a4 = a2 * a2, a8 = a4 * a4, a16 = a8 * a8;           \
        float lf = (l4 == 0) ? a8 * a4 : (l4 == 1) ? a8 : (l4 == 2) ? a4 : 1.f;\
        float e = 0.f;                                                         \
        _Pragma("unroll")                                                      \
        for (int i = 0; i < 4; ++i) {                                          \
            unsigned short h0 = bf16bits(acc[i][j][0]);                        \
            unsigned short h1 = bf16bits(acc[i][j][1]);                        \
            unsigned short h2 = bf16bits(acc[i][j][2]);                        \
            unsigned short h3 = bf16bits(acc[i][j][3]);                        \
            float inner = bfbits(h0);                                          \
            inner = fmaf(inner, a, bfbits(h1));                                \
            inner = fmaf(inner, a, bfbits(h2));                                \
            inner = fmaf(inner, a, bfbits(h3));                                \
            e = fmaf(e, a16, inner);                                           \
            int row0 = i * 16 + l4 * 4;                                        \
            *(unsigned short*)(P + (row0    ) * PSTR + s * 2) = h0;            \
            *(unsigned short*)(P + (row0 + 1) * PSTR + s * 2) = h1;            \
            *(unsigned short*)(P + (row0 + 2) * PSTR + s * 2) = h2;            \
            *(unsigned short*)(P + (row0 + 3) * PSTR + s * 2) = h3;            \
        }                                                                      \
        e *= lf;                                                               \
        e += __shfl_xor(e, 16);                                                \
        e += __shfl_xor(e, 32);                                                \
        if (l4 == 0) e64[((size_t)(cc) * B_ + b) * S_ + s] = e;                \
    }

    // Wave-stripe copy: wave w copies bytes [w*64,(w+1)*64) of each row
    // (exactly what it wrote -> same-wave dep, NO barrier).
#define STRIPECOPY(cc)                                                         \
    {                                                                          \
        char* gp = (char*)(ub + ((size_t)b * T_ + (cc) * WND) * S_) + w * 64;  \
        const int lrow = lane >> 2, lo = (lane & 3) * 16;                      \
        _Pragma("unroll")                                                      \
        for (int k = 0; k < 4; ++k) {                                          \
            int row = k * 16 + lrow;                                           \
            uint4 v = *(uint4*)(P + row * PSTR + w * 64 + lo);                 \
            *(uint4*)(gp + (size_t)row * 512 + lo) = v;                        \
        }                                                                      \
    }

    // ---- stage BOTH chunks, then ONE barrier ----
    float4 xr[4], xr1[4];
    LOADX(xr, c0)
    LOADX(xr1, c0 + 1)                 // all 8 loads in flight together
    CVTWRITE(A0, xr)
    CVTWRITE(A1, xr1)
    __syncthreads();                   // A0 + A1 ready (cross-wave)

    {   // ---- chunk 0: MFMA -> epilogue -> stripe-copy (barrier-free) ----
        f32x4 acc[4][2] = {};
        __builtin_amdgcn_s_setprio(1);
        MFMA_TILE(A0)
        __builtin_amdgcn_s_setprio(0);
        EPILOGUE(c0)
        STRIPECOPY(c0)
    }
    {   // ---- chunk 1: immediately follows in wave program order ----
        f32x4 acc[4][2] = {};
        __builtin_amdgcn_s_setprio(1);
        MFMA_TILE(A1)
        __builtin_amdgcn_s_setprio(0);
        EPILOGUE(c0 + 1)
        STRIPECOPY(c0 + 1)
    }
}

// ---------------- K3: fused carry + per-chunk scan + out, x2 s-vectorized --
// Block (c,g): wave w -> b = g*2 + (w>>1), s-half = (w&1); lane -> 2 s values.
// Carry: if all lanes' aw^16 < 1e-10 (true for this data), chunks older than
// 16 contribute < 1e-10 -> 16-trip predicated loop; else exact 64-trip loop.
__global__ __launch_bounds__(256) void k_scan(
        const __hip_bfloat16* __restrict__ ub, const float* __restrict__ e64,
        const float* __restrict__ abar, const float* __restrict__ a64,
        const float* __restrict__ z0, float* __restrict__ out) {
    const int c = blockIdx.x, g = blockIdx.y;
    const int w = threadIdx.x >> 6, lane = threadIdx.x & 63;
    const int b = g * 2 + (w >> 1);
    const int s0 = (w & 1) * 128 + lane * 2;

    float2 a  = *(const float2*)(abar + s0);
    float2 aw = *(const float2*)(a64 + s0);
    float2 z  = *(const float2*)(z0 + b * S_ + s0);

    float p16x = aw.x * aw.x; p16x *= p16x; p16x *= p16x; p16x *= p16x;
    float p16y = aw.y * aw.y; p16y *= p16y; p16y *= p16y; p16y *= p16y;
    if (__all(fmaxf(p16x, p16y) < 1e-10f)) {
        // short path: only the last 16 chunks matter (residual < 1e-10)
        float2 ev[16];
#pragma unroll
        for (int k = 0; k < 16; ++k) {
            int cp = c - 16 + k, cpc = cp < 0 ? 0 : cp;
            ev[k] = *(const float2*)(e64 + ((size_t)cpc * B_ + b) * S_ + s0);
        }
#pragma unroll
        for (int k = 0; k < 16; ++k) {
            float zx = fmaf(aw.x, z.x, ev[k].x);
            float zy = fmaf(aw.y, z.y, ev[k].y);
            bool p = (c - 16 + k) >= 0;
            z.x = p ? zx : z.x;
            z.y = p ? zy : z.y;
        }
    } else {
        // exact path: 64 fixed trips, batch-16 loads then predicated fma
#pragma unroll
        for (int cp0 = 0; cp0 < C4; cp0 += 16) {
            float2 ev[16];
#pragma unroll
            for (int k = 0; k < 16; ++k)
                ev[k] = *(const float2*)(e64 + ((size_t)(cp0 + k) * B_ + b) * S_ + s0);
#pragma unroll
            for (int k = 0; k < 16; ++k) {
                float zx = fmaf(aw.x, z.x, ev[k].x);
                float zy = fmaf(aw.y, z.y, ev[k].y);
                bool p = (cp0 + k) < c;
                z.x = p ? zx : z.x;
                z.y = p ? zy : z.y;
            }
        }
    }

    // scan own chunk, coalesced; nontemporal out stores
    const char* up = (const char*)(ub + ((size_t)b * T_ + c * WND) * S_ + s0);
    float* op = out + ((size_t)(c * WND) * B_ + b) * S_ + s0;
#pragma unroll 8
    for (int t = 0; t < WND; ++t) {
        ushort2 v = *(const ushort2*)up;           // 4 B/lane, 256 B/wave
        z.x = fmaf(a.x, z.x, bfbits(v.x));
        z.y = fmaf(a.y, z.y, bfbits(v.y));
        __builtin_nontemporal_store(z.x, op);
        __builtin_nontemporal_store(z.y, op + 1);
        up += S_ * 2;
        op += (size_t)B_ * S_;
    }
}

extern "C" void kernel_launch(void* const* d_in, const int* in_sizes, int n_in,
                              void* d_out, int out_size, void* d_ws, size_t ws_size,
                              hipStream_t stream) {
    const float* x   = (const float*)d_in[0];  // [T,B,D]
    const float* z0  = (const float*)d_in[1];  // [B,S]
    const float* lna = (const float*)d_in[2];  // [S]
    const float* bm  = (const float*)d_in[3];  // [S,D]
    const float* ldt = (const float*)d_in[4];  // [S]
    float* out = (float*)d_out;

    char* ws = (char*)d_ws;
    float*          abar = (float*)ws;                        // 1 KiB
    float*          a64  = (float*)(ws + 4096);               // 1 KiB
    __hip_bfloat16* bbar = (__hip_bfloat16*)(ws + 8192);      // 64 KiB
    float*          e64  = (float*)(ws + (128 << 10));        // 1 MiB [c][b][s]
    __hip_bfloat16* ub   = (__hip_bfloat16*)(ws + (4 << 20)); // 32 MiB [b][t][s]

    k_params<<<129, 256, 0, stream>>>(lna, bm, ldt, abar, a64, bbar);
    k_gemm<<<dim3(C4 / 2, B_), 512, 0, stream>>>(x, bbar, abar, ub, e64);
    k_scan<<<dim3(C4, B_ / 2), 256, 0, stream>>>(ub, e64, abar, a64, z0, out);
}

// Round 24
// 44.230 us; speedup vs baseline: 1.1107x; 1.0156x over previous
//
#include <hip/hip_runtime.h>
#include <hip/hip_bf16.h>

// Problem constants (S4Layer: T=4096, B=16, D=128, S=256)
#define T_  4096
#define B_  16
#define D_  128
#define S_  256
#define WND 64             // chunk length = GEMM t-tile
#define C4  (T_/WND)       // 64 chunks
#define PSTR 520           // P row stride (pad-8: conflict-free u16 writes)

using bf8   = __attribute__((ext_vector_type(8))) short;   // 8 bf16 (4 VGPRs)
using f32x4 = __attribute__((ext_vector_type(4))) float;   // MFMA acc

__device__ inline float bfbits(unsigned short h) {
    return __builtin_bit_cast(float, (unsigned)h << 16);
}
__device__ inline unsigned short bf16bits(float f) {
    return __hip_bfloat16_raw(__float2bfloat16(f)).x;
}

// ---------------- K1: parameters (hoisted, computed ONCE) -------------------
__global__ __launch_bounds__(256) void k_params(
        const float* __restrict__ lna, const float* __restrict__ bmat,
        const float* __restrict__ ldt,
        float* __restrict__ abar, float* __restrict__ a64,
        __hip_bfloat16* __restrict__ bbar) {
    if (blockIdx.x < 128) {
        int idx = blockIdx.x * 256 + threadIdx.x;   // (s,d)
        int s = idx >> 7;
        float la = fminf(fmaxf(lna[s], -8.f), 4.f);
        float ar = -expf(la);
        float lt = fminf(fmaxf(ldt[s], -8.f), 1.f);
        float dt = expf(lt);
        float xx = dt * ar;
        float ratio = (fabsf(xx) < 1e-6f) ? dt : (expm1f(xx) / ar);
        bbar[idx] = __float2bfloat16(ratio * bmat[idx]);
    } else {
        int s = threadIdx.x;
        float la = fminf(fmaxf(lna[s], -8.f), 4.f);
        float ar = -expf(la);
        float lt = fminf(fmaxf(ldt[s], -8.f), 1.f);
        float dt = expf(lt);
        float ab = expf(dt * ar);
        abar[s] = ab;
        float p = ab;
#pragma unroll
        for (int j = 0; j < 6; ++j) p *= p;     // a^64 by squaring
        a64[s] = p;
    }
}

// ---------------- K2: 8-wave 2-barrier double-buffered GEMM + e64 ----------
// Block (bx,b), 512 threads = 8 waves, chunks c0=2bx, c0+1 (R20 pipeline).
// Wave w owns s-stripe [w*32,(w+1)*32): epilogue writes + copy-out are
// wave-private (P row stride 520B, no XOR -> stripes never cross) => zero
// P barriers; only the two A-stage barriers remain. 16 waves/CU (2 blocks).
__global__ __launch_bounds__(512, 4) void k_gemm(
        const float* __restrict__ x, const __hip_bfloat16* __restrict__ bbar,
        const float* __restrict__ abar,
        __hip_bfloat16* __restrict__ ub, float* __restrict__ e64) {
    const int c0 = blockIdx.x * 2, b = blockIdx.y;
    __shared__ char LDS[32768 + WND * PSTR];   // A0 @0, A1 @16K, P @32K
    char* A0 = LDS;
    char* A1 = LDS + 16384;
    char* P  = LDS + 32768;
    const int tid = threadIdx.x, lane = tid & 63, w = tid >> 6;   // w in 0..7
    const int l15 = lane & 15, l4 = lane >> 4;
    const int srow = tid >> 5, sseg = tid & 31;    // stage: 16 rows x 32 segs

    // B fragments: wave w owns s in [w*32,(w+1)*32), j = 0,1
    bf8 bfrag[2][4];
#pragma unroll
    for (int j = 0; j < 2; ++j) {
        int s = w * 32 + j * 16 + l15;
#pragma unroll
        for (int kk = 0; kk < 4; ++kk)
            bfrag[j][kk] = *(const bf8*)((const short*)bbar + s * D_ + kk * 32 + l4 * 8);
    }

#define LOADX(dst, cc)                                                         \
    _Pragma("unroll")                                                          \
    for (int k = 0; k < 4; ++k)                                                \
        dst[k] = *(const float4*)(x + ((size_t)((cc) * WND + srow + k * 16) * B_ + b) * D_ + sseg * 4);

#define CVTWRITE(A, src)                                                       \
    _Pragma("unroll")                                                          \
    for (int k = 0; k < 4; ++k) {                                              \
        int row = srow + k * 16;                                               \
        __hip_bfloat162 lo = __float22bfloat162_rn(make_float2(src[k].x, src[k].y)); \
        __hip_bfloat162 hi = __float22bfloat162_rn(make_float2(src[k].z, src[k].w)); \
        uint2 pk = { *(unsigned*)&lo, *(unsigned*)&hi };                       \
        *(uint2*)((A) + ((row * 256 + sseg * 8) ^ ((row & 7) << 4))) = pk;     \
    }

#define MFMA_TILE(A)                                                           \
    _Pragma("unroll")                                                          \
    for (int i = 0; i < 4; ++i) {                                              \
        bf8 af[4];                                                             \
        int tr = i * 16 + l15;                                                 \
        _Pragma("unroll")                                                      \
        for (int kk = 0; kk < 4; ++kk) {                                       \
            int off = (tr * 256 + kk * 64 + l4 * 16) ^ ((tr & 7) << 4);        \
            af[kk] = *(const bf8*)((A) + off);                                 \
        }                                                                      \
        _Pragma("unroll")                                                      \
        for (int j = 0; j < 2; ++j)                                            \
            _Pragma("unroll")                                                  \
            for (int kk = 0; kk < 4; ++kk)                                     \
                acc[i][j] = __builtin_amdgcn_mfma_f32_16x16x32_bf16(           \
                                af[kk], bfrag[j][kk], acc[i][j], 0, 0, 0);     \
    }

    // Epilogue: P[row][s] at row stride 520B. Banks: dword = row*130 + s/2;
    // l4 contributes l4*520%32 = {0,8,16,24}, l15 an 8-dword run -> 32 banks,
    // 2 lanes/bank (same dword, free) => conflict-free without XOR.
#define EPILOGUE(cc)                                                           \
    _Pragma("unroll")                                                          \
    for (int j = 0; j < 2; ++j) {                                              \
        int s = w * 32 + j * 16 + l15;                                         \
        float a  = abar[s];                                                    \
        float a2 = a * a, a4 = a2 * a2, a8 = a4 * a4, a16 = a8 * a8;           \
        float lf = (l4 == 0) ? a8 * a4 : (l4 == 1) ? a8 : (l4 == 2) ? a4 : 1.f;\
        float e = 0.f;                                                         \
        _Pragma("unroll")                                                      \
        for (int i = 0; i < 4; ++i) {                                          \
            unsigned short h0 = bf16bits(acc[i][j][0]);                        \
            unsigned short h1 = bf16bits(acc[i][j][1]);                        \
            unsigned short h2 = bf16bits(acc[i][j][2]);                        \
            unsigned short h3 = bf16bits(acc[i][j][3]);                        \
            float inner = bfbits(h0);                                          \
            inner = fmaf(inner, a, bfbits(h1));                                \
            inner = fmaf(inner, a, bfbits(h2));                                \
            inner = fmaf(inner, a, bfbits(h3));                                \
            e = fmaf(e, a16, inner);                                           \
            int row0 = i * 16 + l4 * 4;                                        \
            *(unsigned short*)(P + (row0    ) * PSTR + s * 2) = h0;            \
            *(unsigned short*)(P + (row0 + 1) * PSTR + s * 2) = h1;            \
            *(unsigned short*)(P + (row0 + 2) * PSTR + s * 2) = h2;            \
            *(unsigned short*)(P + (row0 + 3) * PSTR + s * 2) = h3;            \
        }                                                                      \
        e *= lf;                                                               \
        e += __shfl_xor(e, 16);                                                \
        e += __shfl_xor(e, 32);                                                \
        if (l4 == 0) e64[((size_t)(cc) * B_ + b) * S_ + s] = e;                \
    }

    // Wave-stripe copy: wave w copies bytes [w*64,(w+1)*64) of each row
    // (exactly what it wrote -> same-wave dep, NO barrier). 4 lanes/row x 16B.
#define STRIPECOPY(cc)                                                         \
    {                                                                          \
        char* gp = (char*)(ub + ((size_t)b * T_ + (cc) * WND) * S_) + w * 64;  \
        const int lrow = lane >> 2, lo = (lane & 3) * 16;                      \
        _Pragma("unroll")                                                      \
        for (int k = 0; k < 4; ++k) {                                          \
            int row = k * 16 + lrow;                                           \
            uint4 v = *(uint4*)(P + row * PSTR + w * 64 + lo);                 \
            *(uint4*)(gp + (size_t)row * 512 + lo) = v;                        \
        }                                                                      \
    }

    float4 xr[4];
    LOADX(xr, c0)
    CVTWRITE(A0, xr)
    __syncthreads();                   // A0 ready (cross-wave)

    float4 xr1[4];
    LOADX(xr1, c0 + 1)                 // issue early; hides under chunk-0

    {   // ---- chunk 0: MFMA -> epilogue -> stripe-copy (barrier-free) ----
        f32x4 acc[4][2] = {};
        MFMA_TILE(A0)
        EPILOGUE(c0)
        STRIPECOPY(c0)
    }
    CVTWRITE(A1, xr1)
    __syncthreads();                   // A1 ready (cross-wave)

    {   // ---- chunk 1: MFMA -> epilogue -> stripe-copy (barrier-free) ----
        f32x4 acc[4][2] = {};
        MFMA_TILE(A1)
        EPILOGUE(c0 + 1)
        STRIPECOPY(c0 + 1)
    }
}

// ---------------- K3: fused carry + per-chunk scan + out, x2 s-vectorized --
// Block (c,g): wave w -> b = g*2 + (w>>1), s-half = (w&1); lane -> 2 s values.
// Carry: if all lanes' aw^16 < 1e-10 (true for this data), chunks older than
// 16 contribute < 1e-10 -> 16-trip predicated loop; else exact 64-trip loop.
__global__ __launch_bounds__(256) void k_scan(
        const __hip_bfloat16* __restrict__ ub, const float* __restrict__ e64,
        const float* __restrict__ abar, const float* __restrict__ a64,
        const float* __restrict__ z0, float* __restrict__ out) {
    const int c = blockIdx.x, g = blockIdx.y;
    const int w = threadIdx.x >> 6, lane = threadIdx.x & 63;
    const int b = g * 2 + (w >> 1);
    const int s0 = (w & 1) * 128 + lane * 2;

    float2 a  = *(const float2*)(abar + s0);
    float2 aw = *(const float2*)(a64 + s0);
    float2 z  = *(const float2*)(z0 + b * S_ + s0);

    float p16x = aw.x * aw.x; p16x *= p16x; p16x *= p16x; p16x *= p16x;
    float p16y = aw.y * aw.y; p16y *= p16y; p16y *= p16y; p16y *= p16y;
    if (__all(fmaxf(p16x, p16y) < 1e-10f)) {
        // short path: only the last 16 chunks matter (residual < 1e-10)
        float2 ev[16];
#pragma unroll
        for (int k = 0; k < 16; ++k) {
            int cp = c - 16 + k, cpc = cp < 0 ? 0 : cp;
            ev[k] = *(const float2*)(e64 + ((size_t)cpc * B_ + b) * S_ + s0);
        }
#pragma unroll
        for (int k = 0; k < 16; ++k) {
            float zx = fmaf(aw.x, z.x, ev[k].x);
            float zy = fmaf(aw.y, z.y, ev[k].y);
            bool p = (c - 16 + k) >= 0;
            z.x = p ? zx : z.x;
            z.y = p ? zy : z.y;
        }
    } else {
        // exact path: 64 fixed trips, batch-16 loads then predicated fma
#pragma unroll
        for (int cp0 = 0; cp0 < C4; cp0 += 16) {
            float2 ev[16];
#pragma unroll
            for (int k = 0; k < 16; ++k)
                ev[k] = *(const float2*)(e64 + ((size_t)(cp0 + k) * B_ + b) * S_ + s0);
#pragma unroll
            for (int k = 0; k < 16; ++k) {
                float zx = fmaf(aw.x, z.x, ev[k].x);
                float zy = fmaf(aw.y, z.y, ev[k].y);
                bool p = (cp0 + k) < c;
                z.x = p ? zx : z.x;
                z.y = p ? zy : z.y;
            }
        }
    }

    // scan own chunk, coalesced; nontemporal out stores
    const char* up = (const char*)(ub + ((size_t)b * T_ + c * WND) * S_ + s0);
    float* op = out + ((size_t)(c * WND) * B_ + b) * S_ + s0;
#pragma unroll 8
    for (int t = 0; t < WND; ++t) {
        ushort2 v = *(const ushort2*)up;           // 4 B/lane, 256 B/wave
        z.x = fmaf(a.x, z.x, bfbits(v.x));
        z.y = fmaf(a.y, z.y, bfbits(v.y));
        __builtin_nontemporal_store(z.x, op);
        __builtin_nontemporal_store(z.y, op + 1);
        up += S_ * 2;
        op += (size_t)B_ * S_;
    }
}

extern "C" void kernel_launch(void* const* d_in, const int* in_sizes, int n_in,
                              void* d_out, int out_size, void* d_ws, size_t ws_size,
                              hipStream_t stream) {
    const float* x   = (const float*)d_in[0];  // [T,B,D]
    const float* z0  = (const float*)d_in[1];  // [B,S]
    const float* lna = (const float*)d_in[2];  // [S]
    const float* bm  = (const float*)d_in[3];  // [S,D]
    const float* ldt = (const float*)d_in[4];  // [S]
    float* out = (float*)d_out;

    char* ws = (char*)d_ws;
    float*          abar = (float*)ws;                        // 1 KiB
    float*          a64  = (float*)(ws + 4096);               // 1 KiB
    __hip_bfloat16* bbar = (__hip_bfloat16*)(ws + 8192);      // 64 KiB
    float*          e64  = (float*)(ws + (128 << 10));        // 1 MiB [c][b][s]
    __hip_bfloat16* ub   = (__hip_bfloat16*)(ws + (4 << 20)); // 32 MiB [b][t][s]

    k_params<<<129, 256, 0, stream>>>(lna, bm, ldt, abar, a64, bbar);
    k_gemm<<<dim3(C4 / 2, B_), 512, 0, stream>>>(x, bbar, abar, ub, e64);
    k_scan<<<dim3(C4, B_ / 2), 256, 0, stream>>>(ub, e64, abar, a64, z0, out);
}